// Round 1
// baseline (49.676 us; speedup 1.0000x reference)
//
#include <hip/hip_runtime.h>
#include <hip/hip_bf16.h>

// FeatureContrast: out[b,i,j,hw] = x[b,c,hw] * exp(w*x[b,c,hw]) / sum_{3x3 window}
// exp(w*x[b,ch,hw]) over the 16x16 channel grid, c = (i+1)*16+(j+1).
// B=32, n=14, n_in=16, HW=64*64=4096.

#define NIN 16
#define NOUT 14
#define HW 4096

__global__ __launch_bounds__(256) void fc_kernel(
    const float* __restrict__ x,
    const float* __restrict__ wp,
    float* __restrict__ out)
{
    const float w = wp[0];
    const int hw = blockIdx.x * blockDim.x + threadIdx.x;   // 0..4095
    const int b  = blockIdx.y;                              // 0..31

    const float* xb = x   + ((size_t)b * (NIN * NIN)) * HW + hw;
    float*       ob = out + ((size_t)b * (NOUT * NOUT)) * HW + hw;

    // Rolling 3 channel-rows of exp values; x of middle row for the numerator.
    float eA[NIN], eB[NIN], eC[NIN];
    float xB[NIN], xC[NIN];

    // Prologue: row 0 -> eA, row 1 -> eB (keep raw x in xB)
    #pragma unroll
    for (int c = 0; c < NIN; ++c) {
        float v = xb[(size_t)c * HW];
        eA[c] = __expf(v * w);
    }
    #pragma unroll
    for (int c = 0; c < NIN; ++c) {
        float v = xb[(size_t)(NIN + c) * HW];
        xB[c] = v;
        eB[c] = __expf(v * w);
    }

    for (int i = 0; i < NOUT; ++i) {
        // Load channel row i+2 -> eC/xC
        #pragma unroll
        for (int c = 0; c < NIN; ++c) {
            float v = xb[(size_t)((i + 2) * NIN + c) * HW];
            xC[c] = v;
            eC[c] = __expf(v * w);
        }

        // Column sums across the 3 rows
        float cs[NIN];
        #pragma unroll
        for (int c = 0; c < NIN; ++c) cs[c] = eA[c] + eB[c] + eC[c];

        // Output row i: denom = 3-wide sum of column sums; numerator from middle row
        #pragma unroll
        for (int j = 0; j < NOUT; ++j) {
            float denom = cs[j] + cs[j + 1] + cs[j + 2];
            float num   = xB[j + 1] * eB[j + 1];
            ob[(size_t)(i * NOUT + j) * HW] = __fdividef(num, denom);
        }

        // Rotate rows (static indices -> stays in registers)
        #pragma unroll
        for (int c = 0; c < NIN; ++c) {
            eA[c] = eB[c];
            eB[c] = eC[c];
            xB[c] = xC[c];
        }
    }
}

extern "C" void kernel_launch(void* const* d_in, const int* in_sizes, int n_in,
                              void* d_out, int out_size, void* d_ws, size_t ws_size,
                              hipStream_t stream) {
    const float* x  = (const float*)d_in[0];
    const float* wp = (const float*)d_in[1];
    // d_in[2] = n (14), d_in[3] = kk (1) — fixed by setup, hardcoded above.
    float* out = (float*)d_out;

    dim3 block(256, 1, 1);
    dim3 grid(HW / 256, 32, 1);   // 16 x 32 = 512 blocks
    hipLaunchKernelGGL(fc_kernel, grid, block, 0, stream, x, wp, out);
}

// Round 2
// 48.787 us; speedup vs baseline: 1.0182x; 1.0182x over previous
//
#include <hip/hip_runtime.h>
#include <hip/hip_bf16.h>

// FeatureContrast: out[b,i,j,hw] = x[b,c,hw] * exp(w*x[b,c,hw]) / sum_{3x3 window}
// exp(w*x[b,ch,hw]) over the 16x16 channel grid, c = (i+1)*16+(j+1).
// B=32, n=14, n_in=16, HW=64*64=4096.
//
// R2: one thread = one output row i for one (b,hw) column. State = cs[16]+num[16]
// (accumulate column sums as the 3 channel rows stream in) -> low VGPR, and the
// grid grows 14x (7168 blocks = 28/CU) to fix the R1 occupancy ceiling (19.7%).
// 3x read amplification is served by L2/L3 (input 134MB < 256MB LLC).

#define NIN 16
#define NOUT 14
#define HW 4096

__global__ __launch_bounds__(256) void fc_kernel(
    const float* __restrict__ x,
    const float* __restrict__ wp,
    float* __restrict__ out)
{
    const float w = wp[0];
    const int hw = blockIdx.x * blockDim.x + threadIdx.x;   // 0..4095
    const int i  = blockIdx.y;                              // output row 0..13
    const int b  = blockIdx.z;                              // 0..31

    // Channel rows i, i+1, i+2 of the 16x16 grid feed output row i.
    const float* xb = x + ((size_t)(b * (NIN * NIN) + i * NIN)) * HW + hw;

    float cs[NIN];   // column sums of exp over the 3 rows
    float num[NIN];  // x * exp(w*x) of the middle row

    // Row i
    #pragma unroll
    for (int c = 0; c < NIN; ++c) {
        float v = xb[(size_t)c * HW];
        cs[c] = __expf(v * w);
    }
    // Row i+1 (middle: numerator source)
    #pragma unroll
    for (int c = 0; c < NIN; ++c) {
        float v = xb[(size_t)(NIN + c) * HW];
        float e = __expf(v * w);
        cs[c] += e;
        num[c] = v * e;
    }
    // Row i+2
    #pragma unroll
    for (int c = 0; c < NIN; ++c) {
        float v = xb[(size_t)(2 * NIN + c) * HW];
        cs[c] += __expf(v * w);
    }

    float* ob = out + ((size_t)(b * (NOUT * NOUT) + i * NOUT)) * HW + hw;
    #pragma unroll
    for (int j = 0; j < NOUT; ++j) {
        float denom = cs[j] + cs[j + 1] + cs[j + 2];
        ob[(size_t)j * HW] = __fdividef(num[j + 1], denom);
    }
}

extern "C" void kernel_launch(void* const* d_in, const int* in_sizes, int n_in,
                              void* d_out, int out_size, void* d_ws, size_t ws_size,
                              hipStream_t stream) {
    const float* x  = (const float*)d_in[0];
    const float* wp = (const float*)d_in[1];
    float* out = (float*)d_out;

    dim3 block(256, 1, 1);
    dim3 grid(HW / 256, NOUT, 32);   // 16 x 14 x 32 = 7168 blocks
    hipLaunchKernelGGL(fc_kernel, grid, block, 0, stream, x, wp, out);
}